// Round 4
// baseline (18064.996 us; speedup 1.0000x reference)
//
#include <hip/hip_runtime.h>
#include <stdint.h>

typedef _Float16 f16;
typedef __attribute__((ext_vector_type(8))) _Float16 f16x8;
typedef __attribute__((ext_vector_type(4))) float f32x4;

#define TT 512
#define FF 3
#define HH 128
#define BB 16384
#define BC 32          // batch rows per block -> 512 blocks, 2 per CU
#define PITCH 296      // hc row pitch in f16
#define NTH 512        // 8 waves, col-split (16 cols x 4 gates each), m=2

// Unified packed weights: Bp[grp(13)][gate(4)][col(128)][ksub(4)][e(8)] f16
//   grp 0..4  : layer0, K=160 (128 h0 + 4 x(data0,data1,data2,delta) + 28 zero)
//   grp 5..12 : layer1, K=256 (128 h0' + 128 h1)
#define NGRP 13
#define GSTRIDE 16384          // elems per group = 4*128*32
#define NBP (NGRP*GSTRIDE)     // 212992 elems
#define WS_BIAS_OFF ((size_t)NBP*2)

__global__ void prep_kernel(
    const float* __restrict__ Wih0, const float* __restrict__ Whh0,
    const float* __restrict__ bih0, const float* __restrict__ bhh0,
    const float* __restrict__ Wih1, const float* __restrict__ Whh1,
    const float* __restrict__ bih1, const float* __restrict__ bhh1,
    f16* __restrict__ Bp, float* __restrict__ biasSum)
{
  int idx = blockIdx.x*256 + threadIdx.x;
  if (idx < NBP){
    int e = idx & 7, ksub = (idx>>3)&3, c = (idx>>5)&127, g = (idx>>12)&3, grp = idx>>14;
    int kl = ksub*8 + e;               // 0..31 within group
    int gcol = g*128 + c;              // row of W (4H)
    float v = 0.f;
    if (grp < 5){
      int k = grp*32 + kl;             // 0..159
      if (k < 128)      v = Whh0[gcol*128 + k];
      else if (k < 132) v = Wih0[gcol*4 + (k - 128)];
    } else {
      int k = (grp-5)*32 + kl;         // 0..255
      v = (k < 128) ? Wih1[gcol*128 + k] : Whh1[gcol*128 + (k - 128)];
    }
    Bp[idx] = (f16)v;
  } else if (idx < NBP + 1024){
    int j = idx - NBP;
    int layer = j >> 9, gcol = j & 511;
    biasSum[j] = layer ? (bih1[gcol] + bhh1[gcol]) : (bih0[gcol] + bhh0[gcol]);
  }
}

__device__ __forceinline__ float clamp15(float x){
  return fminf(fmaxf(x, -15.f), 15.f);
}

__global__ __attribute__((amdgpu_flat_work_group_size(NTH, NTH), amdgpu_waves_per_eu(4, 4)))
void lstm_kernel(
    const float* __restrict__ data, const float* __restrict__ PnL,
    const f16*  __restrict__ Bp,   const float* __restrict__ biasSum,
    const float* __restrict__ fcW, const float* __restrict__ fcb,
    const int* __restrict__ ploc,  float* __restrict__ out)
{
  // per-buffer cols: [0,128) h0 | [128,256) h1 | [256,259) x | 259 delta | [260,288) zeros
  __shared__ __align__(16) f16 hc[2*BC*PITCH];     // 37888 B
  __shared__ float fcw_s[HH];                       // 512 B
  __shared__ float dbuf[BC][16];                    // 2048 B  (out-store staging)
  __shared__ float pnlbuf[BC];                      // 128 B

  const int tid = threadIdx.x;
  const int w   = tid >> 6;        // wave 0..7
  const int l   = tid & 63;
  const int l15 = l & 15;
  const int lhi = l >> 4;          // 0..3
  const int jc  = w*16 + l15;      // owned gate-column 0..127
  const int bg0 = blockIdx.x * BC;

  for (int i = tid; i < 2*BC*PITCH; i += NTH) hc[i] = (f16)0.f;
  if (tid < HH) fcw_s[tid] = fcW[tid];

  float bias0[4], bias1[4];
#pragma unroll
  for (int g = 0; g < 4; ++g){
    bias0[g] = biasSum[g*HH + jc];
    bias1[g] = biasSum[512 + g*HH + jc];
  }
  const float fcb0 = fcb[0];
  const int   pl   = ploc[0];
  const f16*  BpL  = Bp + jc*32 + lhi*8;   // per-lane weight base

  __syncthreads();
  // stage x(0) into buffer 0 (delta(-1)=0 via zero-init); zero out[:,0]
  if (tid < 128 && (tid & 3))
    hc[(tid>>2)*PITCH + 255 + (tid&3)] = (f16)data[(size_t)(bg0 + (tid>>2))*TT*FF + (tid&3) - 1];
  if (tid < BC) out[(size_t)(bg0 + tid)*513] = 0.f;

  float cs0[8], cs1[8];
#pragma unroll
  for (int e = 0; e < 8; ++e){ cs0[e] = 0.f; cs1[e] = 0.f; }

  const int rowD = tid >> 4;   // delta-phase row 0..31
  const int subD = tid & 15;   // 16 lanes/row, 8 cols each
  float pnl = 0.f, dold = 0.f;

  __syncthreads();

#define LOADG(dst, grp_) \
  { const f16* _p = BpL + (grp_)*GSTRIDE; \
    dst[0] = *(const f16x8*)(_p); \
    dst[1] = *(const f16x8*)(_p + 4096); \
    dst[2] = *(const f16x8*)(_p + 8192); \
    dst[3] = *(const f16x8*)(_p + 12288); }

  for (int t = 0; t < TT; ++t){
    const f16* Ab = &hc[(t & 1) * (BC*PITCH)];        // read buffer
    f16*       Qb = &hc[((t & 1) ^ 1) * (BC*PITCH)];  // write buffer

    // flush previous 16-step delta window as full-line stores
    if (t && (t & 15) == 0)
      out[(size_t)(bg0 + rowD)*513 + (t - 15) + subD] = dbuf[rowD][subD];

    // weight ring (depth 2) + data hoists
    f16x8 ring[2][4];
    LOADG(ring[0], 0);
    LOADG(ring[1], 1);
    float price_r = 0.f;
    if (subD == 0)
      price_r = data[(size_t)((bg0 + rowD)*TT + t)*FF + pl];
    float xnv = 0.f;
    const bool do_stage = (t < TT-1) && (tid < 128) && (tid & 3);
    if (do_stage)
      xnv = data[(size_t)((bg0 + (tid>>2))*TT + (t+1))*FF + (tid&3) - 1];

    f32x4 acc[2][4];
    // ========== G0: gates0 = [h0(t-1), x(t)] @ W0^T + b   (groups 0..4) ==========
#pragma unroll
    for (int g = 0; g < 4; ++g){
      f32x4 v = {bias0[g], bias0[g], bias0[g], bias0[g]};
      acc[0][g] = v; acc[1][g] = v;
    }
#pragma unroll
    for (int ks = 0; ks < 5; ++ks){
      const int colA = (ks < 4 ? ks*32 : 256) + 8*lhi;
#pragma unroll
      for (int m = 0; m < 2; ++m){
        f16x8 a = *(const f16x8*)&Ab[(m*16 + l15)*PITCH + colA];
#pragma unroll
        for (int g = 0; g < 4; ++g)
          acc[m][g] = __builtin_amdgcn_mfma_f32_16x16x32_f16(a, ring[ks & 1][g], acc[m][g], 0, 0, 0);
      }
      LOADG(ring[ks & 1], ks + 2);   // groups 2..6
    }

    // ========== cell 0 ==========
#pragma unroll
    for (int m = 0; m < 2; ++m){
#pragma unroll
      for (int r = 0; r < 4; ++r){
        const int e = m*4 + r;
        float iv = acc[m][0][r], fv = acc[m][1][r];
        float gv = clamp15(acc[m][2][r]), ov = acc[m][3][r];
        float ea = __expf(-iv), eb = __expf(2.f*gv), ef = __expf(-fv);
        float it = (eb - 1.f) * __builtin_amdgcn_rcpf((1.f + ea)*(1.f + eb));
        float c  = __builtin_amdgcn_rcpf(1.f + ef)*cs0[e] + it;
        cs0[e] = c;
        float cc = clamp15(c);
        float ew = __expf(2.f*cc), eo = __expf(-ov);
        float h  = (ew - 1.f) * __builtin_amdgcn_rcpf((1.f + eo)*(1.f + ew));
        Qb[(m*16 + lhi*4 + r)*PITCH + jc] = (f16)h;
      }
    }
    __syncthreads();   // (B1) h0(t) visible; Ab.h0/x reads done

    // ========== G1: gates1 = [h0(t), h1(t-1)] @ W1^T + b   (groups 5..12) ==========
#pragma unroll
    for (int g = 0; g < 4; ++g){
      f32x4 v = {bias1[g], bias1[g], bias1[g], bias1[g]};
      acc[0][g] = v; acc[1][g] = v;
    }
#pragma unroll
    for (int ks = 0; ks < 8; ++ks){
      const int  grp  = 5 + ks;
      const int  slot = grp & 1;
      const f16* ap   = (ks < 4) ? Qb : Ab;   // h0(t) then h1(t-1)
      const int  colA = ks*32 + 8*lhi;
#pragma unroll
      for (int m = 0; m < 2; ++m){
        f16x8 a = *(const f16x8*)&ap[(m*16 + l15)*PITCH + colA];
#pragma unroll
        for (int g = 0; g < 4; ++g)
          acc[m][g] = __builtin_amdgcn_mfma_f32_16x16x32_f16(a, ring[slot][g], acc[m][g], 0, 0, 0);
      }
      if (grp + 2 <= 12) LOADG(ring[slot], grp + 2);
    }

    // ========== cell 1 ==========
#pragma unroll
    for (int m = 0; m < 2; ++m){
#pragma unroll
      for (int r = 0; r < 4; ++r){
        const int e = m*4 + r;
        float iv = acc[m][0][r], fv = acc[m][1][r];
        float gv = clamp15(acc[m][2][r]), ov = acc[m][3][r];
        float ea = __expf(-iv), eb = __expf(2.f*gv), ef = __expf(-fv);
        float it = (eb - 1.f) * __builtin_amdgcn_rcpf((1.f + ea)*(1.f + eb));
        float c  = __builtin_amdgcn_rcpf(1.f + ef)*cs1[e] + it;
        cs1[e] = c;
        float cc = clamp15(c);
        float ew = __expf(2.f*cc), eo = __expf(-ov);
        float h  = (ew - 1.f) * __builtin_amdgcn_rcpf((1.f + eo)*(1.f + ew));
        Qb[(m*16 + lhi*4 + r)*PITCH + 128 + jc] = (f16)h;
      }
    }
    __syncthreads();   // (B2) h1(t) visible

    // ========== delta = h1(t) @ fcW^T + fcb ; pnl ; restage x(t+1) ==========
    {
      f16x8 v = *(const f16x8*)&Qb[rowD*PITCH + 128 + subD*8];
      float s = 0.f;
#pragma unroll
      for (int u = 0; u < 8; ++u) s += (float)v[u] * fcw_s[subD*8 + u];
      s += __shfl_xor(s, 1);
      s += __shfl_xor(s, 2);
      s += __shfl_xor(s, 4);
      s += __shfl_xor(s, 8);
      if (subD == 0){
        const float dnew = s + fcb0;
        pnl += (dold - dnew) * price_r;
        dbuf[rowD][t & 15] = dnew;
        Qb[rowD*PITCH + 259] = (f16)dnew;
        dold = dnew;
        if (t == TT-1){
          const float lastp = data[(size_t)((bg0 + rowD)*TT + (TT-1))*FF + 0];
          pnlbuf[rowD] = pnl + dnew*lastp;
        }
      }
      if (do_stage)
        Qb[(tid>>2)*PITCH + 255 + (tid&3)] = (f16)xnv;
    }
    __syncthreads();   // (B3) Qb complete -> becomes read buffer
  }

  // final window flush (steps 496..511 -> out indices 497..512) and pnl
  out[(size_t)(bg0 + rowD)*513 + 497 + subD] = dbuf[rowD][subD];
  if (tid < BC)
    out[(size_t)BB*513 + bg0 + tid] = pnlbuf[tid] + PnL[bg0 + tid];
#undef LOADG
}

extern "C" void kernel_launch(void* const* d_in, const int* in_sizes, int n_in,
                              void* d_out, int out_size, void* d_ws, size_t ws_size,
                              hipStream_t stream)
{
  const float* data = (const float*)d_in[0];
  const float* PnL  = (const float*)d_in[1];
  const float* Wih0 = (const float*)d_in[2];
  const float* Whh0 = (const float*)d_in[3];
  const float* bih0 = (const float*)d_in[4];
  const float* bhh0 = (const float*)d_in[5];
  const float* Wih1 = (const float*)d_in[6];
  const float* Whh1 = (const float*)d_in[7];
  const float* bih1 = (const float*)d_in[8];
  const float* bhh1 = (const float*)d_in[9];
  const float* fcW  = (const float*)d_in[10];
  const float* fcb  = (const float*)d_in[11];
  const int*   ploc = (const int*)d_in[12];

  f16*   Bp      = (f16*)d_ws;
  float* biasSum = (float*)((char*)d_ws + WS_BIAS_OFF);
  float* out     = (float*)d_out;

  const int prepN = NBP + 1024;
  prep_kernel<<<(prepN + 255)/256, 256, 0, stream>>>(
      Wih0, Whh0, bih0, bhh0, Wih1, Whh1, bih1, bhh1, Bp, biasSum);
  lstm_kernel<<<BB/BC, NTH, 0, stream>>>(
      data, PnL, Bp, biasSum, fcW, fcb, ploc, out);
}

// Round 6
// 6266.395 us; speedup vs baseline: 2.8828x; 2.8828x over previous
//
#include <hip/hip_runtime.h>
#include <stdint.h>

typedef _Float16 f16;
typedef __attribute__((ext_vector_type(8))) _Float16 f16x8;
typedef __attribute__((ext_vector_type(4))) float f32x4;

#define TT 512
#define FF 3
#define HH 128
#define BB 16384
#define BC 32          // batch rows per block -> 512 blocks, 1 per CU (LDS-forced), 2 rounds
#define PITCH 296      // hc row pitch in f16 (592 B = 148 dw, 148 mod 32 = 20 -> 2-way banks)
#define NTH 512        // 8 waves, col-split (16 cols x 4 gates each), m=2
#define WP 40          // wlds row pitch in f16 (80 B)

// Packed weights: Bp[grp(13)][gate(4)][col(128)][ksub(4)][e(8)] f16
//   grp 0..4  : layer0, K=160 (128 h0 + 4 x + 28 zero)
//   grp 5..12 : layer1, K=256 (128 h0' + 128 h1)
// Runtime: groups 0..9 live in registers (160 VGPR), groups 10..12 in LDS.
#define NGRP 13
#define GSTRIDE 16384
#define NBP (NGRP*GSTRIDE)
#define WS_BIAS_OFF ((size_t)NBP*2)

__global__ void prep_kernel(
    const float* __restrict__ Wih0, const float* __restrict__ Whh0,
    const float* __restrict__ bih0, const float* __restrict__ bhh0,
    const float* __restrict__ Wih1, const float* __restrict__ Whh1,
    const float* __restrict__ bih1, const float* __restrict__ bhh1,
    f16* __restrict__ Bp, float* __restrict__ biasSum)
{
  int idx = blockIdx.x*256 + threadIdx.x;
  if (idx < NBP){
    int e = idx & 7, ksub = (idx>>3)&3, c = (idx>>5)&127, g = (idx>>12)&3, grp = idx>>14;
    int kl = ksub*8 + e;               // 0..31 within group
    int gcol = g*128 + c;              // row of W (4H)
    float v = 0.f;
    if (grp < 5){
      int k = grp*32 + kl;             // 0..159
      if (k < 128)      v = Whh0[gcol*128 + k];
      else if (k < 132) v = Wih0[gcol*4 + (k - 128)];
    } else {
      int k = (grp-5)*32 + kl;         // 0..255
      v = (k < 128) ? Wih1[gcol*128 + k] : Whh1[gcol*128 + (k - 128)];
    }
    Bp[idx] = (f16)v;
  } else if (idx < NBP + 1024){
    int j = idx - NBP;
    int layer = j >> 9, gcol = j & 511;
    biasSum[j] = layer ? (bih1[gcol] + bhh1[gcol]) : (bih0[gcol] + bhh0[gcol]);
  }
}

__device__ __forceinline__ float clamp15(float x){
  return fminf(fmaxf(x, -15.f), 15.f);
}

__global__ __launch_bounds__(NTH)
void lstm_kernel(
    const float* __restrict__ data, const float* __restrict__ PnL,
    const f16*  __restrict__ Bp,   const float* __restrict__ biasSum,
    const float* __restrict__ fcW, const float* __restrict__ fcb,
    const int* __restrict__ ploc,  float* __restrict__ out)
{
  // hc cols: [0,128) h0 | [128,256) h1 | [256,259) x | 259 delta | [260,296) zero
  __shared__ __align__(16) f16 hc[2*BC*PITCH];        // 37,888 B (double buffer)
  __shared__ __align__(16) f16 wlds[3*512*WP];        // 122,880 B (groups 10..12)
  __shared__ float fcw_s[HH];                          // 512 B
  __shared__ float dbuf[BC][16];                       // 2,048 B
  __shared__ float pnlbuf[BC];                         // 128 B
  // total 163,456 B -> 1 block/CU -> 2 waves/SIMD -> 256-reg budget per wave

  const int tid = threadIdx.x;
  const int w   = tid >> 6;        // wave 0..7
  const int l   = tid & 63;
  const int l15 = l & 15;
  const int lhi = l >> 4;          // 0..3
  const int jc  = w*16 + l15;      // owned gate-column 0..127
  const int bg0 = blockIdx.x * BC;

  for (int i = tid; i < 2*BC*PITCH; i += NTH) hc[i] = (f16)0.f;
  if (tid < HH) fcw_s[tid] = fcW[tid];

  // stage weight groups 10..12 into LDS (once)
  for (int i = tid; i < 3*4*128*4; i += NTH){
    int ksub = i & 3, col = (i>>2)&127, g = (i>>9)&3, grp3 = i>>11;
    *(f16x8*)&wlds[((grp3*512) + g*128 + col)*WP + ksub*8] =
      *(const f16x8*)(Bp + (10+grp3)*GSTRIDE + g*4096 + col*32 + ksub*8);
  }

  float bias0[4], bias1[4];
#pragma unroll
  for (int g = 0; g < 4; ++g){
    bias0[g] = biasSum[g*HH + jc];
    bias1[g] = biasSum[512 + g*HH + jc];
  }
  const float fcb0 = fcb[0];
  const int   pl   = ploc[0];

  // ---- persistent weights: groups 0..9 -> 40 x f16x8 = 160 VGPR ----
  f16x8 wr[10][4];
  {
    const f16* BpL = Bp + jc*32 + lhi*8;
#pragma unroll
    for (int grp = 0; grp < 10; ++grp)
#pragma unroll
      for (int g = 0; g < 4; ++g)
        wr[grp][g] = *(const f16x8*)(BpL + grp*GSTRIDE + g*4096);
  }

  __syncthreads();
  // stage x(0) into buffer 0 (delta(-1)=0 via zero-init); zero out[:,0]
  if (tid < 128 && (tid & 3))
    hc[(tid>>2)*PITCH + 255 + (tid&3)] = (f16)data[(size_t)(bg0 + (tid>>2))*TT*FF + (tid&3) - 1];
  if (tid < BC) __builtin_nontemporal_store(0.f, &out[(size_t)(bg0 + tid)*513]);

  float cs0[8], cs1[8];
#pragma unroll
  for (int e = 0; e < 8; ++e){ cs0[e] = 0.f; cs1[e] = 0.f; }

  const int rowD = tid >> 4;   // delta-phase row 0..31
  const int subD = tid & 15;   // 16 lanes/row, 8 cols each
  float pnl = 0.f, dold = 0.f;

  __syncthreads();

  for (int t = 0; t < TT; ++t){
    const f16* Ab = &hc[(t & 1) * (BC*PITCH)];        // read buffer
    f16*       Qb = &hc[((t & 1) ^ 1) * (BC*PITCH)];  // write buffer

    // flush previous 16-step delta window as coalesced stores
    if (t && (t & 15) == 0)
      __builtin_nontemporal_store(dbuf[rowD][subD],
          &out[(size_t)(bg0 + rowD)*513 + (t - 15) + subD]);

    // hoist this step's tiny global loads
    float price_r = 0.f;
    if (subD == 0)
      price_r = data[(size_t)((bg0 + rowD)*TT + t)*FF + pl];
    float xnv = 0.f;
    const bool do_stage = (t < TT-1) && (tid < 128) && (tid & 3);
    if (do_stage)
      xnv = data[(size_t)((bg0 + (tid>>2))*TT + (t+1))*FF + (tid&3) - 1];

    f32x4 acc[2][4];
    // ========== G0: gates0 = [h0(t-1), x(t)] @ W0^T + b   (reg groups 0..4) ==========
#pragma unroll
    for (int g = 0; g < 4; ++g){
      f32x4 v = {bias0[g], bias0[g], bias0[g], bias0[g]};
      acc[0][g] = v; acc[1][g] = v;
    }
#pragma unroll
    for (int ks = 0; ks < 5; ++ks){
      const int colA = (ks < 4 ? ks*32 : 256) + 8*lhi;  // ks=4: cols 256..287, in-bounds, zero-padded
#pragma unroll
      for (int m = 0; m < 2; ++m){
        f16x8 a = *(const f16x8*)&Ab[(m*16 + l15)*PITCH + colA];
#pragma unroll
        for (int g = 0; g < 4; ++g)
          acc[m][g] = __builtin_amdgcn_mfma_f32_16x16x32_f16(a, wr[ks][g], acc[m][g], 0, 0, 0);
      }
    }

    // ========== cell 0 ==========
#pragma unroll
    for (int m = 0; m < 2; ++m){
#pragma unroll
      for (int r = 0; r < 4; ++r){
        const int e = m*4 + r;
        float iv = acc[m][0][r], fv = acc[m][1][r];
        float gv = clamp15(acc[m][2][r]), ov = acc[m][3][r];
        float ea = __expf(-iv), eb = __expf(2.f*gv), ef = __expf(-fv);
        float it = (eb - 1.f) * __builtin_amdgcn_rcpf((1.f + ea)*(1.f + eb));
        float c  = __builtin_amdgcn_rcpf(1.f + ef)*cs0[e] + it;
        cs0[e] = c;
        float cc = clamp15(c);
        float ew = __expf(2.f*cc), eo = __expf(-ov);
        float h  = (ew - 1.f) * __builtin_amdgcn_rcpf((1.f + eo)*(1.f + ew));
        Qb[(m*16 + lhi*4 + r)*PITCH + jc] = (f16)h;
      }
    }
    __syncthreads();   // (B1) h0(t) visible

    // ========== G1: gates1 = [h0(t), h1(t-1)] @ W1^T + b ==========
    //   ks 0..4 -> reg groups 5..9 ; ks 5..7 -> LDS groups 0..2
#pragma unroll
    for (int g = 0; g < 4; ++g){
      f32x4 v = {bias1[g], bias1[g], bias1[g], bias1[g]};
      acc[0][g] = v; acc[1][g] = v;
    }
#pragma unroll
    for (int ks = 0; ks < 8; ++ks){
      const f16* ap   = (ks < 4) ? Qb : Ab;   // h0(t) then h1(t-1)
      const int  colA = ks*32 + 8*lhi;
      f16x8 a0 = *(const f16x8*)&ap[(l15)*PITCH + colA];
      f16x8 a1 = *(const f16x8*)&ap[(16 + l15)*PITCH + colA];
#pragma unroll
      for (int g = 0; g < 4; ++g){
        f16x8 bf;
        if (ks < 5) bf = wr[5 + ks][g];
        else        bf = *(const f16x8*)&wlds[(((ks-5)*512) + g*128 + jc)*WP + lhi*8];
        acc[0][g] = __builtin_amdgcn_mfma_f32_16x16x32_f16(a0, bf, acc[0][g], 0, 0, 0);
        acc[1][g] = __builtin_amdgcn_mfma_f32_16x16x32_f16(a1, bf, acc[1][g], 0, 0, 0);
      }
    }

    // ========== cell 1 ==========
#pragma unroll
    for (int m = 0; m < 2; ++m){
#pragma unroll
      for (int r = 0; r < 4; ++r){
        const int e = m*4 + r;
        float iv = acc[m][0][r], fv = acc[m][1][r];
        float gv = clamp15(acc[m][2][r]), ov = acc[m][3][r];
        float ea = __expf(-iv), eb = __expf(2.f*gv), ef = __expf(-fv);
        float it = (eb - 1.f) * __builtin_amdgcn_rcpf((1.f + ea)*(1.f + eb));
        float c  = __builtin_amdgcn_rcpf(1.f + ef)*cs1[e] + it;
        cs1[e] = c;
        float cc = clamp15(c);
        float ew = __expf(2.f*cc), eo = __expf(-ov);
        float h  = (ew - 1.f) * __builtin_amdgcn_rcpf((1.f + eo)*(1.f + ew));
        Qb[(m*16 + lhi*4 + r)*PITCH + 128 + jc] = (f16)h;
      }
    }
    __syncthreads();   // (B2) h1(t) visible

    // ========== delta = h1(t) @ fcW^T + fcb ; pnl ; restage x(t+1) ==========
    {
      f16x8 v = *(const f16x8*)&Qb[rowD*PITCH + 128 + subD*8];
      float s = 0.f;
#pragma unroll
      for (int u = 0; u < 8; ++u) s += (float)v[u] * fcw_s[subD*8 + u];
      s += __shfl_xor(s, 1);
      s += __shfl_xor(s, 2);
      s += __shfl_xor(s, 4);
      s += __shfl_xor(s, 8);
      if (subD == 0){
        const float dnew = s + fcb0;
        pnl += (dold - dnew) * price_r;
        dbuf[rowD][t & 15] = dnew;
        Qb[rowD*PITCH + 259] = (f16)dnew;
        dold = dnew;
        if (t == TT-1){
          const float lastp = data[(size_t)((bg0 + rowD)*TT + (TT-1))*FF + 0];
          pnlbuf[rowD] = pnl + dnew*lastp;
        }
      }
      if (do_stage)
        Qb[(tid>>2)*PITCH + 255 + (tid&3)] = (f16)xnv;
    }
    __syncthreads();   // (B3) Qb complete -> becomes read buffer
  }

  // final window flush (out cols 497..512) and pnl
  __builtin_nontemporal_store(dbuf[rowD][subD],
      &out[(size_t)(bg0 + rowD)*513 + 497 + subD]);
  if (tid < BC)
    out[(size_t)BB*513 + bg0 + tid] = pnlbuf[tid] + PnL[bg0 + tid];
}

extern "C" void kernel_launch(void* const* d_in, const int* in_sizes, int n_in,
                              void* d_out, int out_size, void* d_ws, size_t ws_size,
                              hipStream_t stream)
{
  const float* data = (const float*)d_in[0];
  const float* PnL  = (const float*)d_in[1];
  const float* Wih0 = (const float*)d_in[2];
  const float* Whh0 = (const float*)d_in[3];
  const float* bih0 = (const float*)d_in[4];
  const float* bhh0 = (const float*)d_in[5];
  const float* Wih1 = (const float*)d_in[6];
  const float* Whh1 = (const float*)d_in[7];
  const float* bih1 = (const float*)d_in[8];
  const float* bhh1 = (const float*)d_in[9];
  const float* fcW  = (const float*)d_in[10];
  const float* fcb  = (const float*)d_in[11];
  const int*   ploc = (const int*)d_in[12];

  f16*   Bp      = (f16*)d_ws;
  float* biasSum = (float*)((char*)d_ws + WS_BIAS_OFF);
  float* out     = (float*)d_out;

  const int prepN = NBP + 1024;
  prep_kernel<<<(prepN + 255)/256, 256, 0, stream>>>(
      Wih0, Whh0, bih0, bhh0, Wih1, Whh1, bih1, bhh1, Bp, biasSum);
  lstm_kernel<<<BB/BC, NTH, 0, stream>>>(
      data, PnL, Bp, biasSum, fcW, fcb, ploc, out);
}